// Round 2
// baseline (96.109 us; speedup 1.0000x reference)
//
#include <hip/hip_runtime.h>
#include <math.h>

#define ALPHA 0.3f
#define K_NBR 32
#define NPB   16
#define NPW   4

__device__ __forceinline__ float leaky_f(float x) { return x >= 0.f ? x : ALPHA * x; }

__global__ __launch_bounds__(256) void k_dense(const float* __restrict__ X,
                                               const float* __restrict__ Qw,
                                               const float* __restrict__ Qb,
                                               float* __restrict__ Hout, int N)
{
    __shared__ float sQ[64 * 64];
    __shared__ float sX[NPB * 64];
    const int tid  = threadIdx.x;
    const int wid  = tid >> 6;
    const int lane = tid & 63;
    const int bstart = blockIdx.x * NPB;
    const bool full  = (bstart + NPB <= N);

    {
        const float4* s = (const float4*)Qw;
        float4* d = (float4*)sQ;
        #pragma unroll
        for (int i = 0; i < 4; ++i) d[i * 256 + tid] = s[i * 256 + tid];
    }
    if (full) {
        ((float4*)sX)[tid] = ((const float4*)(X + (size_t)bstart * 64))[tid];
    } else {
        #pragma unroll
        for (int j = 0; j < NPW; ++j) {
            int slot = wid * NPW + j;
            int n = bstart + slot; if (n >= N) n = N - 1;
            sX[slot * 64 + lane] = X[(size_t)n * 64 + lane];
        }
    }
    __syncthreads();

    const float qb = Qb[lane];
    float acc[NPW];
    #pragma unroll
    for (int j = 0; j < NPW; ++j) acc[j] = qb;
    #pragma unroll
    for (int c = 0; c < 64; ++c) {
        float qv = sQ[c * 64 + lane];
        #pragma unroll
        for (int j = 0; j < NPW; ++j)
            acc[j] = fmaf(sX[(wid * NPW + j) * 64 + c], qv, acc[j]);
    }
    #pragma unroll
    for (int j = 0; j < NPW; ++j) {
        int n = bstart + wid * NPW + j;
        if (n < N) Hout[(size_t)n * 64 + lane] = leaky_f(acc[j]);
    }
}

__global__ __launch_bounds__(256) void k_conv_fused(
    const float* __restrict__ X,
    const float* __restrict__ Hbuf,
    const float* __restrict__ Wmat,
    const int*  __restrict__ nbr,
    float* __restrict__ wcache,
    const float* __restrict__ Ww,
    const float* __restrict__ Wb,
    const float* __restrict__ Qw,
    const float* __restrict__ Qb,
    float* __restrict__ OUT,
    float* __restrict__ H1out,
    int N)
{
    __shared__ float sW[128 * 64];
    __shared__ float sQ[64 * 64];
    __shared__ float sx[NPB * 64];
    __shared__ float sa[NPB * 64];
    __shared__ int   snb[NPB * K_NBR];
    __shared__ float sw[NPB * K_NBR];

    const int tid  = threadIdx.x;
    const int wid  = tid >> 6;
    const int lane = tid & 63;
    const int bstart = blockIdx.x * NPB;
    const bool full  = (bstart + NPB <= N);

    int   gid[2];
    float gw[2];
    #pragma unroll
    for (int u = 0; u < 2; ++u) {
        int p    = tid + u * 256;
        int slot = p >> 5;
        int n    = bstart + slot; if (n >= N) n = N - 1;
        int id   = nbr[(size_t)n * K_NBR + (p & 31)];
        gid[u]   = id;
        gw[u]    = Wmat[(size_t)n * N + id];
    }

    {
        const float4* s1 = (const float4*)Ww; float4* d1 = (float4*)sW;
        #pragma unroll
        for (int i = 0; i < 8; ++i) d1[i * 256 + tid] = s1[i * 256 + tid];
        const float4* s2 = (const float4*)Qw; float4* d2 = (float4*)sQ;
        #pragma unroll
        for (int i = 0; i < 4; ++i) d2[i * 256 + tid] = s2[i * 256 + tid];
    }
    if (full) {
        ((float4*)sx)[tid] = ((const float4*)(X + (size_t)bstart * 64))[tid];
    } else {
        #pragma unroll
        for (int j = 0; j < NPW; ++j) {
            int slot = wid * NPW + j;
            int n = bstart + slot; if (n >= N) n = N - 1;
            sx[slot * 64 + lane] = X[(size_t)n * 64 + lane];
        }
    }
    #pragma unroll
    for (int u = 0; u < 2; ++u) {
        int p = tid + u * 256;
        snb[p] = gid[u];
        sw[p]  = gw[u];
    }
    __syncthreads();

    if (wcache) {
        if (full) {
            if (tid < 128)
                ((float4*)(wcache + (size_t)bstart * K_NBR))[tid] = ((float4*)sw)[tid];
        } else {
            #pragma unroll
            for (int u = 0; u < 2; ++u) {
                int p = tid + u * 256;
                if (bstart + (p >> 5) < N) wcache[(size_t)bstart * K_NBR + p] = sw[p];
            }
        }
    }

    float sumw[NPW], agg[NPW];
    #pragma unroll
    for (int j = 0; j < NPW; ++j) {
        int slot = wid * NPW + j;
        float s = 0.f;
        #pragma unroll
        for (int k = 0; k < K_NBR; ++k) s += sw[slot * K_NBR + k];
        sumw[j] = s;
        agg[j]  = 0.f;
    }
    #pragma unroll 4
    for (int k = 0; k < K_NBR; ++k) {
        #pragma unroll
        for (int j = 0; j < NPW; ++j) {
            int slot = wid * NPW + j;
            size_t id = (size_t)snb[slot * K_NBR + k];
            agg[j] = fmaf(sw[slot * K_NBR + k], Hbuf[id * 64 + lane], agg[j]);
        }
    }
    #pragma unroll
    for (int j = 0; j < NPW; ++j)
        sa[(wid * NPW + j) * 64 + lane] = agg[j] / (sumw[j] + 1e-6f);
    __syncthreads();

    const float wb = Wb[lane];
    float acc[NPW];
    #pragma unroll
    for (int j = 0; j < NPW; ++j) acc[j] = wb;
    #pragma unroll
    for (int c = 0; c < 64; ++c) {
        float wv = sW[c * 64 + lane];
        #pragma unroll
        for (int j = 0; j < NPW; ++j)
            acc[j] = fmaf(sx[(wid * NPW + j) * 64 + c], wv, acc[j]);
    }
    #pragma unroll
    for (int c = 0; c < 64; ++c) {
        float wv = sW[(64 + c) * 64 + lane];
        #pragma unroll
        for (int j = 0; j < NPW; ++j)
            acc[j] = fmaf(sa[(wid * NPW + j) * 64 + c], wv, acc[j]);
    }

    float onorm[NPW];
    #pragma unroll
    for (int j = 0; j < NPW; ++j) {
        float o = leaky_f(acc[j]);
        float ss = o * o;
        #pragma unroll
        for (int off = 32; off; off >>= 1) ss += __shfl_xor(ss, off);
        o = o / (sqrtf(ss) + 1e-6f);
        onorm[j] = o;
        int n = bstart + wid * NPW + j;
        if (n < N) OUT[(size_t)n * 64 + lane] = o;
    }

    #pragma unroll
    for (int j = 0; j < NPW; ++j)
        sx[(wid * NPW + j) * 64 + lane] = onorm[j];
    __syncthreads();

    const float qb = Qb[lane];
    float acc1[NPW];
    #pragma unroll
    for (int j = 0; j < NPW; ++j) acc1[j] = qb;
    #pragma unroll
    for (int c = 0; c < 64; ++c) {
        float qv = sQ[c * 64 + lane];
        #pragma unroll
        for (int j = 0; j < NPW; ++j)
            acc1[j] = fmaf(sx[(wid * NPW + j) * 64 + c], qv, acc1[j]);
    }
    #pragma unroll
    for (int j = 0; j < NPW; ++j) {
        int n = bstart + wid * NPW + j;
        if (n < N) H1out[(size_t)n * 64 + lane] = leaky_f(acc1[j]);
    }
}

__global__ __launch_bounds__(256) void k_conv(
    const float* __restrict__ X,
    const float* __restrict__ Hbuf,
    const float* __restrict__ Wmat,
    const int*  __restrict__ nbr,
    const float* __restrict__ wcache,
    const float* __restrict__ Ww,
    const float* __restrict__ Wb,
    float* __restrict__ OUT,
    int N, int mode)
{
    __shared__ float sW[128 * 64];
    __shared__ float sx[NPB * 64];
    __shared__ float sa[NPB * 64];
    __shared__ int   snb[NPB * K_NBR];
    __shared__ float sw[NPB * K_NBR];

    const int tid  = threadIdx.x;
    const int wid  = tid >> 6;
    const int lane = tid & 63;
    const int bstart = blockIdx.x * NPB;
    const bool full  = (bstart + NPB <= N);

    int   gid[2];
    float gw[2];
    #pragma unroll
    for (int u = 0; u < 2; ++u) {
        int p    = tid + u * 256;
        int slot = p >> 5;
        int n    = bstart + slot; if (n >= N) n = N - 1;
        int id   = nbr[(size_t)n * K_NBR + (p & 31)];
        gid[u]   = id;
        if (mode == 1) gw[u] = wcache[(size_t)n * K_NBR + (p & 31)];
        else           gw[u] = Wmat[(size_t)n * N + id];
    }

    {
        const float4* s1 = (const float4*)Ww; float4* d1 = (float4*)sW;
        #pragma unroll
        for (int i = 0; i < 8; ++i) d1[i * 256 + tid] = s1[i * 256 + tid];
    }
    if (full) {
        ((float4*)sx)[tid] = ((const float4*)(X + (size_t)bstart * 64))[tid];
    } else {
        #pragma unroll
        for (int j = 0; j < NPW; ++j) {
            int slot = wid * NPW + j;
            int n = bstart + slot; if (n >= N) n = N - 1;
            sx[slot * 64 + lane] = X[(size_t)n * 64 + lane];
        }
    }
    #pragma unroll
    for (int u = 0; u < 2; ++u) {
        int p = tid + u * 256;
        snb[p] = gid[u];
        sw[p]  = gw[u];
    }
    __syncthreads();

    float sumw[NPW], agg[NPW];
    #pragma unroll
    for (int j = 0; j < NPW; ++j) {
        int slot = wid * NPW + j;
        float s = 0.f;
        #pragma unroll
        for (int k = 0; k < K_NBR; ++k) s += sw[slot * K_NBR + k];
        sumw[j] = s;
        agg[j]  = 0.f;
    }
    #pragma unroll 4
    for (int k = 0; k < K_NBR; ++k) {
        #pragma unroll
        for (int j = 0; j < NPW; ++j) {
            int slot = wid * NPW + j;
            size_t id = (size_t)snb[slot * K_NBR + k];
            agg[j] = fmaf(sw[slot * K_NBR + k], Hbuf[id * 64 + lane], agg[j]);
        }
    }
    #pragma unroll
    for (int j = 0; j < NPW; ++j)
        sa[(wid * NPW + j) * 64 + lane] = agg[j] / (sumw[j] + 1e-6f);
    __syncthreads();

    const float wb = Wb[lane];
    float acc[NPW];
    #pragma unroll
    for (int j = 0; j < NPW; ++j) acc[j] = wb;
    #pragma unroll
    for (int c = 0; c < 64; ++c) {
        float wv = sW[c * 64 + lane];
        #pragma unroll
        for (int j = 0; j < NPW; ++j)
            acc[j] = fmaf(sx[(wid * NPW + j) * 64 + c], wv, acc[j]);
    }
    #pragma unroll
    for (int c = 0; c < 64; ++c) {
        float wv = sW[(64 + c) * 64 + lane];
        #pragma unroll
        for (int j = 0; j < NPW; ++j)
            acc[j] = fmaf(sa[(wid * NPW + j) * 64 + c], wv, acc[j]);
    }

    #pragma unroll
    for (int j = 0; j < NPW; ++j) {
        float o = leaky_f(acc[j]);
        float ss = o * o;
        #pragma unroll
        for (int off = 32; off; off >>= 1) ss += __shfl_xor(ss, off);
        int n = bstart + wid * NPW + j;
        if (n < N) OUT[(size_t)n * 64 + lane] = o / (sqrtf(ss) + 1e-6f);
    }
}

extern "C" void kernel_launch(void* const* d_in, const int* in_sizes, int n_in,
                              void* d_out, int out_size, void* d_ws, size_t ws_size,
                              hipStream_t stream)
{
    const float* emb  = (const float*)d_in[0];
    const float* wmat = (const float*)d_in[1];
    const int*   nbr  = (const int*)  d_in[2];
    const float* Q0w  = (const float*)d_in[3];
    const float* Q0b  = (const float*)d_in[4];
    const float* W0w  = (const float*)d_in[5];
    const float* W0b  = (const float*)d_in[6];
    const float* Q1w  = (const float*)d_in[7];
    const float* Q1b  = (const float*)d_in[8];
    const float* W1w  = (const float*)d_in[9];
    const float* W1b  = (const float*)d_in[10];
    float* out = (float*)d_out;

    const int N = in_sizes[2] / K_NBR;
    const size_t hbuf_bytes = (size_t)N * 64 * sizeof(float);
    const size_t wc_bytes   = (size_t)N * K_NBR * sizeof(float);

    float* hbuf = (float*)d_ws;                               // h0
    float* h1   = (float*)((char*)d_ws + hbuf_bytes);         // h1 (disjoint!)
    bool use_wc = ws_size >= 2 * hbuf_bytes + wc_bytes;
    float* wcache = use_wc ? (float*)((char*)d_ws + 2 * hbuf_bytes) : nullptr;

    const int grid = (N + NPB - 1) / NPB;

    k_dense<<<grid, 256, 0, stream>>>(emb, Q0w, Q0b, hbuf, N);
    k_conv_fused<<<grid, 256, 0, stream>>>(emb, hbuf, wmat, nbr, wcache,
                                           W0w, W0b, Q1w, Q1b, out, h1, N);
    k_conv<<<grid, 256, 0, stream>>>(out, h1, wmat, nbr, wcache,
                                     W1w, W1b, out, N, use_wc ? 1 : 0);
}

// Round 3
// 88.360 us; speedup vs baseline: 1.0877x; 1.0877x over previous
//
#include <hip/hip_runtime.h>
#include <math.h>

#define ALPHA 0.3f
#define K_NBR 32
#define NPB   16
#define NPW   4

__device__ __forceinline__ float leaky_f(float x) { return x >= 0.f ? x : ALPHA * x; }

// ---------------------------------------------------------------------------
// k_dense: Hout[n,h] = leaky( sum_c X[n,c]*Qw[c,h] + Qb[h] )
// 16 nodes/block, 4 waves x 4 nodes. Regular compute, W staged in LDS.
// ---------------------------------------------------------------------------
__global__ __launch_bounds__(256) void k_dense(const float* __restrict__ X,
                                               const float* __restrict__ Qw,
                                               const float* __restrict__ Qb,
                                               float* __restrict__ Hout, int N)
{
    __shared__ float sQ[64 * 64];
    __shared__ float sX[NPB * 64];
    const int tid  = threadIdx.x;
    const int wid  = tid >> 6;
    const int lane = tid & 63;
    const int bstart = blockIdx.x * NPB;
    const bool full  = (bstart + NPB <= N);

    {
        const float4* s = (const float4*)Qw;
        float4* d = (float4*)sQ;
        #pragma unroll
        for (int i = 0; i < 4; ++i) d[i * 256 + tid] = s[i * 256 + tid];
    }
    if (full) {
        ((float4*)sX)[tid] = ((const float4*)(X + (size_t)bstart * 64))[tid];
    } else {
        #pragma unroll
        for (int j = 0; j < NPW; ++j) {
            int slot = wid * NPW + j;
            int n = bstart + slot; if (n >= N) n = N - 1;
            sX[slot * 64 + lane] = X[(size_t)n * 64 + lane];
        }
    }
    __syncthreads();

    const float qb = Qb[lane];
    float acc[NPW] = {qb, qb, qb, qb};
    const float4* sX4 = (const float4*)sX;
    #pragma unroll
    for (int c4 = 0; c4 < 16; ++c4) {
        float4 xv[NPW];
        #pragma unroll
        for (int j = 0; j < NPW; ++j) xv[j] = sX4[(wid * NPW + j) * 16 + c4];
        #pragma unroll
        for (int u = 0; u < 4; ++u) {
            float qv = sQ[(c4 * 4 + u) * 64 + lane];
            #pragma unroll
            for (int j = 0; j < NPW; ++j)
                acc[j] = fmaf((&xv[j].x)[u], qv, acc[j]);
        }
    }
    #pragma unroll
    for (int j = 0; j < NPW; ++j) {
        int n = bstart + wid * NPW + j;
        if (n < N) Hout[(size_t)n * 64 + lane] = leaky_f(acc[j]);
    }
}

// ---------------------------------------------------------------------------
// k_gather: AGG[n,h] = sum_k w_k * H[nbr[n,k], h] / (sum_k w_k + 1e-6)
//   mode 0: w_k = Wmat[n, nbr[n,k]], cached to wc_out
//   mode 1: w_k = wc[n,k]
// One node per wave, ZERO LDS (ids/weights via __shfl), max occupancy.
// ---------------------------------------------------------------------------
__global__ __launch_bounds__(256) void k_gather(
    const float* __restrict__ H,
    const float* __restrict__ Wmat,
    const float* __restrict__ wc,
    float* __restrict__ wc_out,
    const int*  __restrict__ nbr,
    float* __restrict__ AGG,
    int N, int mode)
{
    const int n = blockIdx.x * 4 + (threadIdx.x >> 6);
    if (n >= N) return;
    const int lane = threadIdx.x & 63;
    const int kk   = lane & 31;     // both wave halves load duplicate copies

    int   id = nbr[(size_t)n * K_NBR + kk];
    float w  = mode ? wc[(size_t)n * K_NBR + kk]
                    : Wmat[(size_t)n * (size_t)N + id];
    if (mode == 0 && wc_out && lane < K_NBR)
        wc_out[(size_t)n * K_NBR + lane] = w;

    float s = w;
    #pragma unroll
    for (int off = 16; off; off >>= 1) s += __shfl_xor(s, off);

    float a0 = 0.f, a1 = 0.f;
    #pragma unroll
    for (int k = 0; k < K_NBR; k += 2) {
        int   i0 = __shfl(id, k);
        float w0 = __shfl(w,  k);
        int   i1 = __shfl(id, k + 1);
        float w1 = __shfl(w,  k + 1);
        a0 = fmaf(w0, H[(size_t)i0 * 64 + lane], a0);
        a1 = fmaf(w1, H[(size_t)i1 * 64 + lane], a1);
    }
    AGG[(size_t)n * 64 + lane] = (a0 + a1) / (s + 1e-6f);
}

// ---------------------------------------------------------------------------
// k_combine: o = leaky([X[n,:], AGG[n,:]] . Ww + Wb); OUT[n] = o/(||o||+1e-6)
// FUSE: additionally H1out[n] = leaky(OUT[n] . Qw + Qb)  (node-local)
// In-place safe on OUT==X (block stages its own rows before writing).
// ---------------------------------------------------------------------------
template<bool FUSE>
__global__ __launch_bounds__(256) void k_combine(
    const float* __restrict__ X,
    const float* __restrict__ AGG,
    const float* __restrict__ Ww,   // 128 x 64
    const float* __restrict__ Wb,
    const float* __restrict__ Qw,   // 64 x 64 (only if FUSE)
    const float* __restrict__ Qb,
    float* __restrict__ OUT,
    float* __restrict__ H1out,
    int N)
{
    __shared__ float sW[128 * 64];
    __shared__ float sQ[FUSE ? 64 * 64 : 4];
    __shared__ float sx[NPB * 64];
    __shared__ float sa[NPB * 64];

    const int tid  = threadIdx.x;
    const int wid  = tid >> 6;
    const int lane = tid & 63;
    const int bstart = blockIdx.x * NPB;
    const bool full  = (bstart + NPB <= N);

    {
        const float4* s1 = (const float4*)Ww; float4* d1 = (float4*)sW;
        #pragma unroll
        for (int i = 0; i < 8; ++i) d1[i * 256 + tid] = s1[i * 256 + tid];
        if (FUSE) {
            const float4* s2 = (const float4*)Qw; float4* d2 = (float4*)sQ;
            #pragma unroll
            for (int i = 0; i < 4; ++i) d2[i * 256 + tid] = s2[i * 256 + tid];
        }
    }
    // x/agg staging is wave-local (thread tid's float4 lands in a row owned
    // by its own wave), so only the sW/sQ staging needs the barrier below.
    if (full) {
        ((float4*)sx)[tid] = ((const float4*)(X   + (size_t)bstart * 64))[tid];
        ((float4*)sa)[tid] = ((const float4*)(AGG + (size_t)bstart * 64))[tid];
    } else {
        #pragma unroll
        for (int j = 0; j < NPW; ++j) {
            int slot = wid * NPW + j;
            int n = bstart + slot; if (n >= N) n = N - 1;
            sx[slot * 64 + lane] = X[(size_t)n * 64 + lane];
            sa[slot * 64 + lane] = AGG[(size_t)n * 64 + lane];
        }
    }
    __syncthreads();

    const float wb = Wb[lane];
    float acc[NPW] = {wb, wb, wb, wb};
    const float4* sx4 = (const float4*)sx;
    const float4* sa4 = (const float4*)sa;
    #pragma unroll
    for (int c4 = 0; c4 < 16; ++c4) {
        float4 xv[NPW], av[NPW];
        #pragma unroll
        for (int j = 0; j < NPW; ++j) {
            xv[j] = sx4[(wid * NPW + j) * 16 + c4];
            av[j] = sa4[(wid * NPW + j) * 16 + c4];
        }
        #pragma unroll
        for (int u = 0; u < 4; ++u) {
            int c = c4 * 4 + u;
            float wv1 = sW[c * 64 + lane];
            float wv2 = sW[(64 + c) * 64 + lane];
            #pragma unroll
            for (int j = 0; j < NPW; ++j) {
                acc[j] = fmaf((&xv[j].x)[u], wv1, acc[j]);
                acc[j] = fmaf((&av[j].x)[u], wv2, acc[j]);
            }
        }
    }

    float onorm[NPW];
    #pragma unroll
    for (int j = 0; j < NPW; ++j) {
        float o = leaky_f(acc[j]);
        float ss = o * o;
        #pragma unroll
        for (int off = 32; off; off >>= 1) ss += __shfl_xor(ss, off);
        o = o / (sqrtf(ss) + 1e-6f);
        onorm[j] = o;
        int n = bstart + wid * NPW + j;
        if (n < N) OUT[(size_t)n * 64 + lane] = o;
    }

    if (FUSE) {
        // reuse sx for out0 rows; wave-local (own rows only), no barrier needed
        #pragma unroll
        for (int j = 0; j < NPW; ++j)
            sx[(wid * NPW + j) * 64 + lane] = onorm[j];

        const float qb = Qb[lane];
        float acc1[NPW] = {qb, qb, qb, qb};
        #pragma unroll
        for (int c4 = 0; c4 < 16; ++c4) {
            float4 xv[NPW];
            #pragma unroll
            for (int j = 0; j < NPW; ++j) xv[j] = sx4[(wid * NPW + j) * 16 + c4];
            #pragma unroll
            for (int u = 0; u < 4; ++u) {
                float qv = sQ[(c4 * 4 + u) * 64 + lane];
                #pragma unroll
                for (int j = 0; j < NPW; ++j)
                    acc1[j] = fmaf((&xv[j].x)[u], qv, acc1[j]);
            }
        }
        #pragma unroll
        for (int j = 0; j < NPW; ++j) {
            int n = bstart + wid * NPW + j;
            if (n < N) H1out[(size_t)n * 64 + lane] = leaky_f(acc1[j]);
        }
    }
}

extern "C" void kernel_launch(void* const* d_in, const int* in_sizes, int n_in,
                              void* d_out, int out_size, void* d_ws, size_t ws_size,
                              hipStream_t stream)
{
    const float* emb  = (const float*)d_in[0];
    const float* wmat = (const float*)d_in[1];
    const int*   nbr  = (const int*)  d_in[2];
    const float* Q0w  = (const float*)d_in[3];
    const float* Q0b  = (const float*)d_in[4];
    const float* W0w  = (const float*)d_in[5];
    const float* W0b  = (const float*)d_in[6];
    const float* Q1w  = (const float*)d_in[7];
    const float* Q1b  = (const float*)d_in[8];
    const float* W1w  = (const float*)d_in[9];
    const float* W1b  = (const float*)d_in[10];
    float* out = (float*)d_out;

    const int N = in_sizes[2] / K_NBR;
    const size_t row_bytes = (size_t)N * 64 * sizeof(float);
    const size_t wc_bytes  = (size_t)N * K_NBR * sizeof(float);

    float* hbuf = (float*)d_ws;                            // h (layer 0 then layer 1)
    float* agg  = (float*)((char*)d_ws + row_bytes);       // agg (reused per layer)
    bool use_wc = ws_size >= 2 * row_bytes + wc_bytes;
    float* wcache = use_wc ? (float*)((char*)d_ws + 2 * row_bytes) : nullptr;

    const int gridD = (N + NPB - 1) / NPB;   // 750
    const int gridG = (N + 3) / 4;           // 3000

    // L0 dense: h0 = leaky(emb.Q0+b)
    k_dense<<<gridD, 256, 0, stream>>>(emb, Q0w, Q0b, hbuf, N);
    // L0 gather: agg0 (+ wcache)
    k_gather<<<gridG, 256, 0, stream>>>(hbuf, wmat, nullptr, wcache, nbr, agg, N, 0);
    // L0 combine + L1 dense: out0 -> d_out, h1 -> hbuf
    k_combine<true><<<gridD, 256, 0, stream>>>(emb, agg, W0w, W0b, Q1w, Q1b,
                                               out, hbuf, N);
    // L1 gather: agg1 (weights from cache if available)
    if (use_wc)
        k_gather<<<gridG, 256, 0, stream>>>(hbuf, nullptr, wcache, nullptr, nbr, agg, N, 1);
    else
        k_gather<<<gridG, 256, 0, stream>>>(hbuf, wmat, nullptr, nullptr, nbr, agg, N, 0);
    // L1 combine (in-place on d_out)
    k_combine<false><<<gridD, 256, 0, stream>>>(out, agg, W1w, W1b, nullptr, nullptr,
                                                out, nullptr, N);
}